// Round 4
// baseline (169.373 us; speedup 1.0000x reference)
//
#include <hip/hip_runtime.h>
#include <hip/hip_bf16.h>

// GAT encoder, N=4096, D=128, H=8.
// k_pack (adj->bitmask, transposed [word][row])
// k_prep (W->Wt f16 transposed, W1->W1t f16 transposed)
// k_wh   (Wh = nodes@W per head -> Whbt f16 [h][d][n]; f1,f2 (x log2e))
// k_m2   (per-head max of f2L + exp tables e2t[h][j] = {exp2(f2), exp2(a*f2)})
// k_attn (fused masked-softmax + PV via exp-table product trick; 64-row blocks,
//         4 waves = 2 row-halves x 2 j-halves; LDS combine; coalesced epilogue)
// k_out  (cat@W1 + b1, elu, +nodes residual, LayerNorm -> out f32)

#define NN 4096
#define ALPHA 0.2f
#define EPSLN 1e-5f
#define LOG2E 1.4426950408889634f

typedef __attribute__((ext_vector_type(8))) _Float16 f16x8;
typedef __attribute__((ext_vector_type(4))) _Float16 f16x4;
typedef __attribute__((ext_vector_type(2))) _Float16 f16x2;
typedef __attribute__((ext_vector_type(4))) float f32x4;
typedef __attribute__((ext_vector_type(4))) int i32x4;

union F16x8 { f16x8 v; f16x2 h[4]; };
union F16x4 { f16x4 v; f16x2 h[2]; };

static __device__ inline f16x2 pkrtz(float a, float b) {
  union { decltype(__builtin_amdgcn_cvt_pkrtz(0.f, 0.f)) r; f16x2 h; } u;
  u.r = __builtin_amdgcn_cvt_pkrtz(a, b);
  return u.h;
}

#if __has_builtin(__builtin_amdgcn_exp2f)
#define EXP2(x) __builtin_amdgcn_exp2f(x)
#else
#define EXP2(x) exp2f(x)
#endif

static __device__ inline unsigned long long sp4(unsigned long long x) {
  x = (x | (x << 24)) & 0x000000FF000000FFULL;
  x = (x | (x << 12)) & 0x000F000F000F000FULL;
  x = (x | (x << 6))  & 0x0303030303030303ULL;
  x = (x | (x << 3))  & 0x1111111111111111ULL;
  return x;
}

// ---------------- k_pack: adj int32 [4096][4096] -> maskT u64 [64 words][4096 rows]
__global__ void k_pack(const int* __restrict__ adj, unsigned long long* __restrict__ maskT) {
  int wv = threadIdx.x >> 6, l = threadIdx.x & 63;
  int gid = blockIdx.x * 4 + wv;
  int row = gid >> 4, chunk = gid & 15;
  i32x4 v = *(const i32x4*)(adj + ((size_t)row << 12) + chunk * 256 + l * 4);
  unsigned long long b0 = __ballot(v.x > 0);
  unsigned long long b1 = __ballot(v.y > 0);
  unsigned long long b2 = __ballot(v.z > 0);
  unsigned long long b3 = __ballot(v.w > 0);
  if (l < 4) {
    int sh = l * 16;
    unsigned long long w = sp4((b0 >> sh) & 0xFFFF)
                         | (sp4((b1 >> sh) & 0xFFFF) << 1)
                         | (sp4((b2 >> sh) & 0xFFFF) << 2)
                         | (sp4((b3 >> sh) & 0xFFFF) << 3);
    maskT[(size_t)(chunk * 4 + l) * NN + row] = w;
  }
}

// ---------------- k_prep
__global__ void k_prep(const float* __restrict__ W, const float* __restrict__ W1,
                       _Float16* __restrict__ Wt, _Float16* __restrict__ W1t) {
  int idx = blockIdx.x * 256 + threadIdx.x;
  if (idx < 131072) {
    int h = idx >> 14, r = idx & 16383, d = r >> 7, e = r & 127;
    Wt[h * 16384 + e * 128 + d] = (_Float16)W[idx];
  } else {
    int j = idx - 131072;
    int k = j >> 7, d = j & 127;
    W1t[d * 1024 + k] = (_Float16)W1[j];
  }
}

// ---------------- k_wh: per head GEMM [4096x128]@[128x128] + f1/f2 dots
__global__ __launch_bounds__(256) void k_wh(const float* __restrict__ nodes,
    const _Float16* __restrict__ Wt, const float* __restrict__ a1,
    const float* __restrict__ a2, _Float16* __restrict__ Whbt,
    float* __restrict__ f1L, float* __restrict__ f2L) {
  int h = blockIdx.y;
  int wv = threadIdx.x >> 6, l = threadIdx.x & 63;
  int lr = l & 15, lg = l >> 4;
  int ibase = blockIdx.x * 64 + wv * 16;
  f32x4 acc[8] = {};
  const float* arow = nodes + (size_t)(ibase + lr) * 128;
  const _Float16* bbase = Wt + h * 16384;
#pragma unroll
  for (int ks = 0; ks < 4; ++ks) {
    int k0 = ks * 32 + lg * 8;
    f32x4 av0 = *(const f32x4*)(arow + k0);
    f32x4 av1 = *(const f32x4*)(arow + k0 + 4);
    F16x8 A;
    A.h[0] = pkrtz(av0[0], av0[1]);
    A.h[1] = pkrtz(av0[2], av0[3]);
    A.h[2] = pkrtz(av1[0], av1[1]);
    A.h[3] = pkrtz(av1[2], av1[3]);
#pragma unroll
    for (int nt = 0; nt < 8; ++nt) {
      f16x8 B = *(const f16x8*)(bbase + (nt * 16 + lr) * 128 + k0);
      acc[nt] = __builtin_amdgcn_mfma_f32_16x16x32_f16(A.v, B, acc[nt], 0, 0, 0);
    }
  }
  // store Whbt[h][e][i] packed f16x4 along i (i = ibase + lg*4 + r, r consecutive)
#pragma unroll
  for (int nt = 0; nt < 8; ++nt) {
    F16x4 o;
    o.h[0] = pkrtz(acc[nt][0], acc[nt][1]);
    o.h[1] = pkrtz(acc[nt][2], acc[nt][3]);
    *(f16x4*)(Whbt + (size_t)(h * 128 + nt * 16 + lr) * NN + ibase + lg * 4) = o.v;
  }
  float a1r[8], a2r[8];
#pragma unroll
  for (int nt = 0; nt < 8; ++nt) {
    a1r[nt] = a1[h * 128 + nt * 16 + lr];
    a2r[nt] = a2[h * 128 + nt * 16 + lr];
  }
#pragma unroll
  for (int r = 0; r < 4; ++r) {
    float s1 = 0.f, s2 = 0.f;
#pragma unroll
    for (int nt = 0; nt < 8; ++nt) { s1 += acc[nt][r] * a1r[nt]; s2 += acc[nt][r] * a2r[nt]; }
    s1 += __shfl_xor(s1, 1, 16); s1 += __shfl_xor(s1, 2, 16);
    s1 += __shfl_xor(s1, 4, 16); s1 += __shfl_xor(s1, 8, 16);
    s2 += __shfl_xor(s2, 1, 16); s2 += __shfl_xor(s2, 2, 16);
    s2 += __shfl_xor(s2, 4, 16); s2 += __shfl_xor(s2, 8, 16);
    if (lr == 0) {
      int i = ibase + lg * 4 + r;
      f1L[h * NN + i] = s1 * LOG2E;
      f2L[h * NN + i] = s2 * LOG2E;
    }
  }
}

// ---------------- k_m2: per-head max of f2L + exp tables
__global__ void k_m2(const float* __restrict__ f2L, float* __restrict__ M2L,
                     float2* __restrict__ e2t) {
  __shared__ float red[4];
  int h = blockIdx.x, t = threadIdx.x;
  float v = -1e30f;
  for (int k = t; k < NN; k += 256) {
    float f = f2L[h * NN + k];
    float2 e; e.x = EXP2(f); e.y = EXP2(ALPHA * f);
    e2t[h * NN + k] = e;
    v = fmaxf(v, f);
  }
#pragma unroll
  for (int off = 1; off < 64; off <<= 1) v = fmaxf(v, __shfl_xor(v, off, 64));
  if ((t & 63) == 0) red[t >> 6] = v;
  __syncthreads();
  if (t == 0) M2L[h] = fmaxf(fmaxf(red[0], red[1]), fmaxf(red[2], red[3]));
}

// ---------------- k_attn
// grid 512 (1D): h = bid&7 (XCD-local heads), rowtile = bid>>3 (64 rows).
// 4 waves: w = rh*2 + jh; wave covers rows rh*32..+32 (2 row-groups per lane),
// j-half jh of each 128-j tile (2 ks of 32 j). Single 33KB LDS tile, 2 barriers/ct.
// Softmax: p = max(E1*e2[j], Ea*e2a[j]) masked (exp-free inner loop).
// End: j-half combine in LDS (f32), coalesced f16 epilogue -> hcat.
__global__ __launch_bounds__(256, 2) void k_attn(const _Float16* __restrict__ Whbt,
    const float* __restrict__ f1L, const float* __restrict__ M2L,
    const float2* __restrict__ e2t, const unsigned long long* __restrict__ maskT,
    _Float16* __restrict__ hcat) {
  // staging tile 32KB; combine regions 2 x [32][132] f32 = 33792B (overlaid)
  __shared__ __align__(16) char BtRaw[33792];
  __shared__ float denL[64];
  int t = threadIdx.x, w = t >> 6, l = t & 63, lr = l & 15, lg = l >> 4;
  int bid = blockIdx.x;
  int h = bid & 7, rt = bid >> 3;
  int rowbase = rt * 64;
  int rh = w >> 1, jh = w & 1;
  int r0 = rowbase + rh * 32 + lr, r1 = r0 + 16;
  float f10 = f1L[h * NN + r0], f11 = f1L[h * NN + r1];
  float M2 = M2L[h];
  float tM0 = f10 + M2, tM1 = f11 + M2;
  float mL0 = fmaxf(tM0, ALPHA * tM0), mL1 = fmaxf(tM1, ALPHA * tM1);
  float E10 = EXP2(f10 - mL0), Ea0 = EXP2(ALPHA * f10 - mL0);
  float E11 = EXP2(f11 - mL1), Ea1 = EXP2(ALPHA * f11 - mL1);
  f32x4 acc0[8] = {}, acc1[8] = {};
  float den0 = 0.f, den1 = 0.f;
  int sd = t >> 4, sc = t & 15;
  const _Float16* src = Whbt + ((size_t)h << 19);
  const float2* ep = e2t + (size_t)h * NN;

  // prologue: tile 0 into regs
  f16x8 stg[8];
#pragma unroll
  for (int pass = 0; pass < 8; ++pass)
    stg[pass] = *(const f16x8*)(src + ((size_t)(pass * 16 + sd) << 12) + ((sc ^ sd) << 3));

  for (int ct = 0; ct < 32; ++ct) {
    __syncthreads();  // previous tile's readers done
#pragma unroll
    for (int pass = 0; pass < 8; ++pass)
      *(f16x8*)(BtRaw + pass * 4096 + t * 16) = stg[pass];
    __syncthreads();  // tile ready
    if (ct + 1 < 32) {
      int jt = (ct + 1) * 128;
#pragma unroll
      for (int pass = 0; pass < 8; ++pass)
        stg[pass] = *(const f16x8*)(src + ((size_t)(pass * 16 + sd) << 12) + jt + ((sc ^ sd) << 3));
    }
    // mask word + exp-pairs for this wave's j-half
    unsigned long long mw0 = maskT[(size_t)(ct * 2 + jh) * NN + r0];
    unsigned long long mw1 = maskT[(size_t)(ct * 2 + jh) * NN + r1];
    int jg0 = ct * 128 + jh * 64 + lg * 8;
    f32x4 q[2][4];
#pragma unroll
    for (int ks = 0; ks < 2; ++ks) {
#pragma unroll
      for (int c = 0; c < 4; ++c)
        q[ks][c] = *(const f32x4*)(ep + jg0 + ks * 32 + c * 2);
    }
#pragma unroll
    for (int ks = 0; ks < 2; ++ks) {
      int jb = jh * 64 + ks * 32 + lg * 8;
      unsigned bits0 = (unsigned)(mw0 >> (ks * 32 + lg * 8));
      unsigned bits1 = (unsigned)(mw1 >> (ks * 32 + lg * 8));
      float p0[8], p1[8];
#pragma unroll
      for (int e = 0; e < 8; ++e) {
        float e2 = q[ks][e >> 1][(e & 1) * 2];
        float e2a = q[ks][e >> 1][(e & 1) * 2 + 1];
        float v0 = fmaxf(E10 * e2, Ea0 * e2a);
        p0[e] = ((bits0 >> e) & 1) ? v0 : 0.f;
        den0 += p0[e];
        float v1 = fmaxf(E11 * e2, Ea1 * e2a);
        p1[e] = ((bits1 >> e) & 1) ? v1 : 0.f;
        den1 += p1[e];
      }
      F16x8 A0, A1;
#pragma unroll
      for (int qq = 0; qq < 4; ++qq) {
        A0.h[qq] = pkrtz(p0[2 * qq], p0[2 * qq + 1]);
        A1.h[qq] = pkrtz(p1[2 * qq], p1[2 * qq + 1]);
      }
#pragma unroll
      for (int nt = 0; nt < 8; ++nt) {
        int byteoff = (nt * 16 + lr) * 256 + ((jb * 2) ^ (lr << 4));
        f16x8 B = *(const f16x8*)((const char*)BtRaw + byteoff);
        acc0[nt] = __builtin_amdgcn_mfma_f32_16x16x32_f16(A0.v, B, acc0[nt], 0, 0, 0);
        acc1[nt] = __builtin_amdgcn_mfma_f32_16x16x32_f16(A1.v, B, acc1[nt], 0, 0, 0);
      }
    }
  }
  // reduce den over the 4 j-subgroups (lg)
  den0 += __shfl_xor(den0, 16, 64); den0 += __shfl_xor(den0, 32, 64);
  den1 += __shfl_xor(den1, 16, 64); den1 += __shfl_xor(den1, 32, 64);

  __syncthreads();  // all waves done reading Bt
  float* reg = (float*)BtRaw + (size_t)rh * 32 * 132;  // this wave's region [32][132]
  // phase 1: jh==0 waves write
  if (jh == 0) {
#pragma unroll
    for (int nt = 0; nt < 8; ++nt)
#pragma unroll
      for (int r = 0; r < 4; ++r) {
        reg[(lg * 4 + r) * 132 + nt * 16 + lr] = acc0[nt][r];
        reg[(16 + lg * 4 + r) * 132 + nt * 16 + lr] = acc1[nt][r];
      }
    if (l < 16) { denL[rh * 32 + lr] = den0; denL[rh * 32 + 16 + lr] = den1; }
  }
  __syncthreads();
  // phase 2: jh==1 waves add
  if (jh == 1) {
#pragma unroll
    for (int nt = 0; nt < 8; ++nt)
#pragma unroll
      for (int r = 0; r < 4; ++r) {
        reg[(lg * 4 + r) * 132 + nt * 16 + lr] += acc0[nt][r];
        reg[(16 + lg * 4 + r) * 132 + nt * 16 + lr] += acc1[nt][r];
      }
    if (l < 16) { denL[rh * 32 + lr] += den0; denL[rh * 32 + 16 + lr] += den1; }
  }
  __syncthreads();
  // epilogue: coalesced /den + elu + f16 store. thread t: row t>>2, 32-col seg t&3
  {
    int row = t >> 2, seg = t & 3;
    const float* rg = (float*)BtRaw + (size_t)(row >> 5) * 32 * 132 + (row & 31) * 132 + seg * 32;
    float rc = __builtin_amdgcn_rcpf(denL[row]);
    _Float16* outp = hcat + (size_t)(rowbase + row) * 1024 + h * 128 + seg * 32;
#pragma unroll
    for (int q8 = 0; q8 < 4; ++q8) {
      f32x4 va = *(const f32x4*)(rg + q8 * 8);
      f32x4 vb = *(const f32x4*)(rg + q8 * 8 + 4);
      float x[8];
#pragma unroll
      for (int c = 0; c < 4; ++c) { x[c] = va[c] * rc; x[4 + c] = vb[c] * rc; }
#pragma unroll
      for (int c = 0; c < 8; ++c) x[c] = x[c] > 0.f ? x[c] : EXP2(x[c] * LOG2E) - 1.f;
      F16x8 o;
      o.h[0] = pkrtz(x[0], x[1]); o.h[1] = pkrtz(x[2], x[3]);
      o.h[2] = pkrtz(x[4], x[5]); o.h[3] = pkrtz(x[6], x[7]);
      *(f16x8*)(outp + q8 * 8) = o.v;
    }
  }
}

// ---------------- k_out: x = elu(cat@W1 + b1); out = LN(nodes + x)
__global__ __launch_bounds__(128) void k_out(const _Float16* __restrict__ hcat,
    const _Float16* __restrict__ W1t, const float* __restrict__ b1,
    const float* __restrict__ nodes, const float* __restrict__ gamma,
    const float* __restrict__ beta, float* __restrict__ out) {
  __shared__ __align__(16) float ys[2][16][132];
  int wv = threadIdx.x >> 6, l = threadIdx.x & 63, lr = l & 15, lg = l >> 4;
  int ibase = blockIdx.x * 32 + wv * 16;
  f32x4 acc[8] = {};
  const _Float16* arow = hcat + (size_t)(ibase + lr) * 1024;
#pragma unroll 4
  for (int ks = 0; ks < 32; ++ks) {
    int k0 = ks * 32 + lg * 8;
    f16x8 A = *(const f16x8*)(arow + k0);
#pragma unroll
    for (int nt = 0; nt < 8; ++nt) {
      f16x8 B = *(const f16x8*)(W1t + (nt * 16 + lr) * 1024 + k0);
      acc[nt] = __builtin_amdgcn_mfma_f32_16x16x32_f16(A, B, acc[nt], 0, 0, 0);
    }
  }
#pragma unroll
  for (int nt = 0; nt < 8; ++nt) {
    float bv = b1[nt * 16 + lr];
#pragma unroll
    for (int r = 0; r < 4; ++r) {
      int i = ibase + lg * 4 + r;
      float x = acc[nt][r] + bv;
      x = x > 0.f ? x : EXP2(x * LOG2E) - 1.f;
      ys[wv][lg * 4 + r][nt * 16 + lr] = x + nodes[(size_t)i * 128 + nt * 16 + lr];
    }
  }
  __syncthreads();
  int row = l >> 2, seg = l & 3;
  float sum = 0.f, sq = 0.f;
  f32x4 vbuf[8];
#pragma unroll
  for (int q = 0; q < 8; ++q) {
    f32x4 v = *(const f32x4*)&ys[wv][row][seg * 32 + q * 4];
    vbuf[q] = v;
    sum += v[0] + v[1] + v[2] + v[3];
    sq += v[0] * v[0] + v[1] * v[1] + v[2] * v[2] + v[3] * v[3];
  }
  sum += __shfl_xor(sum, 1, 4); sum += __shfl_xor(sum, 2, 4);
  sq += __shfl_xor(sq, 1, 4); sq += __shfl_xor(sq, 2, 4);
  float mu = sum * (1.f / 128.f);
  float var = sq * (1.f / 128.f) - mu * mu;
  float rs = __builtin_amdgcn_rsqf(var + EPSLN);
  int i = ibase + row;
#pragma unroll
  for (int q = 0; q < 8; ++q) {
    int d = seg * 32 + q * 4;
    f32x4 g = *(const f32x4*)(gamma + d);
    f32x4 bb = *(const f32x4*)(beta + d);
    f32x4 o;
#pragma unroll
    for (int c = 0; c < 4; ++c) o[c] = (vbuf[q][c] - mu) * rs * g[c] + bb[c];
    *(f32x4*)(out + (size_t)i * 128 + d) = o;
  }
}

extern "C" void kernel_launch(void* const* d_in, const int* in_sizes, int n_in,
                              void* d_out, int out_size, void* d_ws, size_t ws_size,
                              hipStream_t stream) {
  const float* nodes = (const float*)d_in[0];
  const int* adj = (const int*)d_in[1];
  const float* W = (const float*)d_in[2];
  const float* a1 = (const float*)d_in[3];
  const float* a2 = (const float*)d_in[4];
  const float* W1 = (const float*)d_in[5];
  const float* b1 = (const float*)d_in[6];
  const float* gamma = (const float*)d_in[7];
  const float* beta = (const float*)d_in[8];
  float* out = (float*)d_out;
  char* ws = (char*)d_ws;

  const size_t OFF_MASK = 0;                       // 2 MB
  const size_t OFF_WHBT = 2097152;                 // 8.4 MB
  const size_t OFF_F1 = OFF_WHBT + 8388608;        // 128 KB
  const size_t OFF_F2 = OFF_F1 + 131072;           // 128 KB
  const size_t OFF_M2 = OFF_F2 + 131072;           // 256 B
  const size_t OFF_E2T = OFF_M2 + 256;             // 256 KB
  const size_t OFF_WT = OFF_E2T + 262144;          // 256 KB
  const size_t OFF_W1T = OFF_WT + 262144;          // 256 KB
  const size_t OFF_HCAT = OFF_W1T + 262144;        // 8.4 MB

  unsigned long long* maskT = (unsigned long long*)(ws + OFF_MASK);
  _Float16* Whbt = (_Float16*)(ws + OFF_WHBT);
  float* f1L = (float*)(ws + OFF_F1);
  float* f2L = (float*)(ws + OFF_F2);
  float* M2L = (float*)(ws + OFF_M2);
  float2* e2t = (float2*)(ws + OFF_E2T);
  _Float16* Wt = (_Float16*)(ws + OFF_WT);
  _Float16* W1t = (_Float16*)(ws + OFF_W1T);
  _Float16* hcat = (_Float16*)(ws + OFF_HCAT);

  k_pack<<<16384, 256, 0, stream>>>(adj, maskT);
  k_prep<<<1024, 256, 0, stream>>>(W, W1, Wt, W1t);
  k_wh<<<dim3(64, 8), 256, 0, stream>>>(nodes, Wt, a1, a2, Whbt, f1L, f2L);
  k_m2<<<8, 256, 0, stream>>>(f2L, M2L, e2t);
  k_attn<<<512, 256, 0, stream>>>(Whbt, f1L, M2L, e2t, maskT, hcat);
  k_out<<<128, 128, 0, stream>>>(hcat, W1t, b1, nodes, gamma, beta, out);
}

// Round 5
// 153.251 us; speedup vs baseline: 1.1052x; 1.1052x over previous
//
#include <hip/hip_runtime.h>
#include <hip/hip_bf16.h>

// GAT encoder, N=4096, D=128, H=8.
// k_packprep (adj->bitmask transposed [word][row]; W/W1 -> f16 transposed)
// k_wh   (Wh = nodes@W per head -> Whbt f16 [h][d][n]; f1,f2 (x log2e))
// k_m2   (per-head max M2 of f2L; tables e2t[h][j] = {exp2(f2-M2), exp2(a(f2-M2))})
// k_attn (fused masked-softmax + PV; 64-row blocks, 256-j LDS tiles (16 iters),
//         swizzled B tile, e2 staged to LDS, prefetched regs; epilogue -> hcat f16)
// k_out  (cat@W1 + b1 with 4-way k-split, elu, +nodes residual, LayerNorm -> f32)

#define NN 4096
#define ALPHA 0.2f
#define EPSLN 1e-5f
#define LOG2E 1.4426950408889634f

typedef __attribute__((ext_vector_type(8))) _Float16 f16x8;
typedef __attribute__((ext_vector_type(4))) _Float16 f16x4;
typedef __attribute__((ext_vector_type(2))) _Float16 f16x2;
typedef __attribute__((ext_vector_type(4))) float f32x4;
typedef __attribute__((ext_vector_type(4))) int i32x4;

union F16x8 { f16x8 v; f16x2 h[4]; };
union F16x4 { f16x4 v; f16x2 h[2]; };

static __device__ inline f16x2 pkrtz(float a, float b) {
  union { decltype(__builtin_amdgcn_cvt_pkrtz(0.f, 0.f)) r; f16x2 h; } u;
  u.r = __builtin_amdgcn_cvt_pkrtz(a, b);
  return u.h;
}

#if __has_builtin(__builtin_amdgcn_exp2f)
#define EXP2(x) __builtin_amdgcn_exp2f(x)
#else
#define EXP2(x) exp2f(x)
#endif

static __device__ inline unsigned long long sp4(unsigned long long x) {
  x = (x | (x << 24)) & 0x000000FF000000FFULL;
  x = (x | (x << 12)) & 0x000F000F000F000FULL;
  x = (x | (x << 6))  & 0x0303030303030303ULL;
  x = (x | (x << 3))  & 0x1111111111111111ULL;
  return x;
}

// ---------------- k_packprep: blocks [0,16384): adj -> maskT; rest: W/W1 -> f16^T
__global__ void k_packprep(const int* __restrict__ adj, unsigned long long* __restrict__ maskT,
                           const float* __restrict__ W, const float* __restrict__ W1,
                           _Float16* __restrict__ Wt, _Float16* __restrict__ W1t) {
  int bid = blockIdx.x;
  if (bid < 16384) {
    int wv = threadIdx.x >> 6, l = threadIdx.x & 63;
    int gid = bid * 4 + wv;
    int row = gid >> 4, chunk = gid & 15;
    i32x4 v = *(const i32x4*)(adj + ((size_t)row << 12) + chunk * 256 + l * 4);
    unsigned long long b0 = __ballot(v.x > 0);
    unsigned long long b1 = __ballot(v.y > 0);
    unsigned long long b2 = __ballot(v.z > 0);
    unsigned long long b3 = __ballot(v.w > 0);
    if (l < 4) {
      int sh = l * 16;
      unsigned long long w = sp4((b0 >> sh) & 0xFFFF)
                           | (sp4((b1 >> sh) & 0xFFFF) << 1)
                           | (sp4((b2 >> sh) & 0xFFFF) << 2)
                           | (sp4((b3 >> sh) & 0xFFFF) << 3);
      maskT[(size_t)(chunk * 4 + l) * NN + row] = w;
    }
  } else {
    int idx = (bid - 16384) * 256 + threadIdx.x;
    if (idx < 131072) {
      int h = idx >> 14, r = idx & 16383, d = r >> 7, e = r & 127;
      Wt[h * 16384 + e * 128 + d] = (_Float16)W[idx];
    } else {
      int j = idx - 131072;
      int k = j >> 7, d = j & 127;
      W1t[d * 1024 + k] = (_Float16)W1[j];
    }
  }
}

// ---------------- k_wh: per head GEMM [4096x128]@[128x128] + f1/f2 dots
__global__ __launch_bounds__(256) void k_wh(const float* __restrict__ nodes,
    const _Float16* __restrict__ Wt, const float* __restrict__ a1,
    const float* __restrict__ a2, _Float16* __restrict__ Whbt,
    float* __restrict__ f1L, float* __restrict__ f2L) {
  int h = blockIdx.y;
  int wv = threadIdx.x >> 6, l = threadIdx.x & 63;
  int lr = l & 15, lg = l >> 4;
  int ibase = blockIdx.x * 64 + wv * 16;
  f32x4 acc[8] = {};
  const float* arow = nodes + (size_t)(ibase + lr) * 128;
  const _Float16* bbase = Wt + h * 16384;
#pragma unroll
  for (int ks = 0; ks < 4; ++ks) {
    int k0 = ks * 32 + lg * 8;
    f32x4 av0 = *(const f32x4*)(arow + k0);
    f32x4 av1 = *(const f32x4*)(arow + k0 + 4);
    F16x8 A;
    A.h[0] = pkrtz(av0[0], av0[1]);
    A.h[1] = pkrtz(av0[2], av0[3]);
    A.h[2] = pkrtz(av1[0], av1[1]);
    A.h[3] = pkrtz(av1[2], av1[3]);
#pragma unroll
    for (int nt = 0; nt < 8; ++nt) {
      f16x8 B = *(const f16x8*)(bbase + (nt * 16 + lr) * 128 + k0);
      acc[nt] = __builtin_amdgcn_mfma_f32_16x16x32_f16(A.v, B, acc[nt], 0, 0, 0);
    }
  }
#pragma unroll
  for (int nt = 0; nt < 8; ++nt) {
    F16x4 o;
    o.h[0] = pkrtz(acc[nt][0], acc[nt][1]);
    o.h[1] = pkrtz(acc[nt][2], acc[nt][3]);
    *(f16x4*)(Whbt + (size_t)(h * 128 + nt * 16 + lr) * NN + ibase + lg * 4) = o.v;
  }
  float a1r[8], a2r[8];
#pragma unroll
  for (int nt = 0; nt < 8; ++nt) {
    a1r[nt] = a1[h * 128 + nt * 16 + lr];
    a2r[nt] = a2[h * 128 + nt * 16 + lr];
  }
#pragma unroll
  for (int r = 0; r < 4; ++r) {
    float s1 = 0.f, s2 = 0.f;
#pragma unroll
    for (int nt = 0; nt < 8; ++nt) { s1 += acc[nt][r] * a1r[nt]; s2 += acc[nt][r] * a2r[nt]; }
    s1 += __shfl_xor(s1, 1, 16); s1 += __shfl_xor(s1, 2, 16);
    s1 += __shfl_xor(s1, 4, 16); s1 += __shfl_xor(s1, 8, 16);
    s2 += __shfl_xor(s2, 1, 16); s2 += __shfl_xor(s2, 2, 16);
    s2 += __shfl_xor(s2, 4, 16); s2 += __shfl_xor(s2, 8, 16);
    if (lr == 0) {
      int i = ibase + lg * 4 + r;
      f1L[h * NN + i] = s1 * LOG2E;
      f2L[h * NN + i] = s2 * LOG2E;
    }
  }
}

// ---------------- k_m2: per-head max of f2L + scaled exp tables (factors <= 1)
__global__ __launch_bounds__(1024) void k_m2(const float* __restrict__ f2L,
    float* __restrict__ M2L, float2* __restrict__ e2t) {
  __shared__ float red[16];
  int h = blockIdx.x, t = threadIdx.x;
  float a[4];
#pragma unroll
  for (int i = 0; i < 4; ++i) a[i] = f2L[h * NN + t + i * 1024];
  float v = fmaxf(fmaxf(a[0], a[1]), fmaxf(a[2], a[3]));
#pragma unroll
  for (int off = 1; off < 64; off <<= 1) v = fmaxf(v, __shfl_xor(v, off, 64));
  if ((t & 63) == 0) red[t >> 6] = v;
  __syncthreads();
  if (t < 16) {
    float m = red[t];
#pragma unroll
    for (int off = 1; off < 16; off <<= 1) m = fmaxf(m, __shfl_xor(m, off, 16));
    if (t == 0) { red[0] = m; M2L[h] = m; }
  }
  __syncthreads();
  float M2 = red[0];
#pragma unroll
  for (int i = 0; i < 4; ++i) {
    float d = a[i] - M2;
    float2 e; e.x = EXP2(d); e.y = EXP2(ALPHA * d);
    e2t[h * NN + t + i * 1024] = e;
  }
}

// ---------------- k_attn
// grid 512 (1D): h = bid&7, rowtile = bid>>3 (64 rows). 4 waves: rh = w>>1 (32-row
// half), jh = w&1 (128-j half of the 256-j tile). 16 tiles, 2 barriers each.
// LDS B tile [128 d][256 j] f16 = 64KB, slot swizzle ^((d&15)<<1) (<=2-way).
// p = max(E1'*e2', Ea'*e2a') masked; all factors <= 1. Epilogue: jh-combine in
// LDS, /den + elu -> hcat f16 [n][h*128+d].
__global__ __launch_bounds__(256, 2) void k_attn(const _Float16* __restrict__ Whbt,
    const float* __restrict__ f1L, const float* __restrict__ M2L,
    const float2* __restrict__ e2t, const unsigned long long* __restrict__ maskT,
    _Float16* __restrict__ hcat) {
  __shared__ __align__(16) char Bt[65536];
  __shared__ __align__(16) float2 e2s[256];
  __shared__ float denL[64];
  int t = threadIdx.x, w = t >> 6, l = t & 63, lr = l & 15, lg = l >> 4;
  int bid = blockIdx.x;
  int h = bid & 7;
  int rowbase = (bid >> 3) * 64;
  int rh = w >> 1, jh = w & 1;
  int r0 = rowbase + rh * 32 + lr, r1 = r0 + 16;
  float f10 = f1L[h * NN + r0], f11 = f1L[h * NN + r1];
  float M2 = M2L[h];
  float s0 = f10 + M2, s1 = f11 + M2;
  float mL0 = fmaxf(s0, ALPHA * s0), mL1 = fmaxf(s1, ALPHA * s1);
  float E10 = EXP2(s0 - mL0), Ea0 = EXP2(ALPHA * s0 - mL0);
  float E11 = EXP2(s1 - mL1), Ea1 = EXP2(ALPHA * s1 - mL1);
  f32x4 acc0[8] = {}, acc1[8] = {};
  float den0 = 0.f, den1 = 0.f;
  int sg = t >> 5, sslot = t & 31;
  const _Float16* src = Whbt + ((size_t)h << 19);
  const float* ep = (const float*)(e2t + (size_t)h * NN);

  // prologue: tile 0 operands into regs (pre-swizzled global source)
  f16x8 stg[16];
  f32x4 estg = {};
  unsigned long long mA0, mA1, mB0, mB1;
#pragma unroll
  for (int p = 0; p < 16; ++p) {
    int d = p * 8 + sg;
    int jc = sslot ^ ((d & 15) << 1);
    stg[p] = *(const f16x8*)(src + (size_t)d * NN + jc * 8);
  }
  if (t < 128) estg = *(const f32x4*)(ep + t * 4);
  mA0 = maskT[(size_t)(jh * 2) * NN + r0];
  mA1 = maskT[(size_t)(jh * 2 + 1) * NN + r0];
  mB0 = maskT[(size_t)(jh * 2) * NN + r1];
  mB1 = maskT[(size_t)(jh * 2 + 1) * NN + r1];

  for (int ct = 0; ct < 16; ++ct) {
    __syncthreads();  // prev tile's readers done
#pragma unroll
    for (int p = 0; p < 16; ++p)
      *(f16x8*)(Bt + p * 4096 + t * 16) = stg[p];
    if (t < 128) *(f32x4*)((float*)e2s + t * 4) = estg;
    unsigned long long w0r0 = mA0, w1r0 = mA1, w0r1 = mB0, w1r1 = mB1;
    __syncthreads();  // tile ready
    if (ct + 1 < 16) {
      int jt = (ct + 1) * 256;
#pragma unroll
      for (int p = 0; p < 16; ++p) {
        int d = p * 8 + sg;
        int jc = sslot ^ ((d & 15) << 1);
        stg[p] = *(const f16x8*)(src + (size_t)d * NN + jt + jc * 8);
      }
      if (t < 128) estg = *(const f32x4*)(ep + jt * 2 + t * 4);
      mA0 = maskT[(size_t)((ct + 1) * 4 + jh * 2) * NN + r0];
      mA1 = maskT[(size_t)((ct + 1) * 4 + jh * 2 + 1) * NN + r0];
      mB0 = maskT[(size_t)((ct + 1) * 4 + jh * 2) * NN + r1];
      mB1 = maskT[(size_t)((ct + 1) * 4 + jh * 2 + 1) * NN + r1];
    }
#pragma unroll
    for (int ks = 0; ks < 4; ++ks) {
      int jb = jh * 128 + ks * 32 + lg * 8;
      const float* e2p = (const float*)e2s + jb * 2;
      f32x4 Q[4];
#pragma unroll
      for (int c = 0; c < 4; ++c) Q[c] = *(const f32x4*)(e2p + c * 4);
      int sh = (ks & 1) * 32 + lg * 8;
      unsigned bits0 = (unsigned)(((ks < 2) ? w0r0 : w1r0) >> sh);
      unsigned bits1 = (unsigned)(((ks < 2) ? w0r1 : w1r1) >> sh);
      float p0[8], p1[8];
#pragma unroll
      for (int e = 0; e < 8; ++e) {
        float e2 = Q[e >> 1][(e & 1) * 2];
        float e2a = Q[e >> 1][(e & 1) * 2 + 1];
        float v0 = fmaxf(E10 * e2, Ea0 * e2a);
        p0[e] = ((bits0 >> e) & 1) ? v0 : 0.f;
        den0 += p0[e];
        float v1 = fmaxf(E11 * e2, Ea1 * e2a);
        p1[e] = ((bits1 >> e) & 1) ? v1 : 0.f;
        den1 += p1[e];
      }
      F16x8 A0, A1;
#pragma unroll
      for (int qq = 0; qq < 4; ++qq) {
        A0.h[qq] = pkrtz(p0[2 * qq], p0[2 * qq + 1]);
        A1.h[qq] = pkrtz(p1[2 * qq], p1[2 * qq + 1]);
      }
      int slot = jb >> 3;
#pragma unroll
      for (int nt = 0; nt < 8; ++nt) {
        int d = nt * 16 + lr;
        int byteoff = d * 512 + ((slot ^ ((d & 15) << 1)) << 4);
        f16x8 B = *(const f16x8*)(Bt + byteoff);
        acc0[nt] = __builtin_amdgcn_mfma_f32_16x16x32_f16(A0.v, B, acc0[nt], 0, 0, 0);
        acc1[nt] = __builtin_amdgcn_mfma_f32_16x16x32_f16(A1.v, B, acc1[nt], 0, 0, 0);
      }
    }
  }
  den0 += __shfl_xor(den0, 16, 64); den0 += __shfl_xor(den0, 32, 64);
  den1 += __shfl_xor(den1, 16, 64); den1 += __shfl_xor(den1, 32, 64);

  __syncthreads();  // all waves done reading Bt
  float* reg = (float*)Bt + (size_t)rh * 32 * 132;
  if (jh == 0) {
#pragma unroll
    for (int nt = 0; nt < 8; ++nt)
#pragma unroll
      for (int r = 0; r < 4; ++r) {
        reg[(lg * 4 + r) * 132 + nt * 16 + lr] = acc0[nt][r];
        reg[(16 + lg * 4 + r) * 132 + nt * 16 + lr] = acc1[nt][r];
      }
    if (l < 16) { denL[rh * 32 + lr] = den0; denL[rh * 32 + 16 + lr] = den1; }
  }
  __syncthreads();
  if (jh == 1) {
#pragma unroll
    for (int nt = 0; nt < 8; ++nt)
#pragma unroll
      for (int r = 0; r < 4; ++r) {
        reg[(lg * 4 + r) * 132 + nt * 16 + lr] += acc0[nt][r];
        reg[(16 + lg * 4 + r) * 132 + nt * 16 + lr] += acc1[nt][r];
      }
    if (l < 16) { denL[rh * 32 + lr] += den0; denL[rh * 32 + 16 + lr] += den1; }
  }
  __syncthreads();
  {
    int row = t >> 2, seg = t & 3;
    const float* rg = (float*)Bt + (size_t)(row >> 5) * 32 * 132 + (row & 31) * 132 + seg * 32;
    float rc = __builtin_amdgcn_rcpf(denL[row]);
    _Float16* outp = hcat + (size_t)(rowbase + row) * 1024 + h * 128 + seg * 32;
#pragma unroll
    for (int q8 = 0; q8 < 4; ++q8) {
      f32x4 va = *(const f32x4*)(rg + q8 * 8);
      f32x4 vb = *(const f32x4*)(rg + q8 * 8 + 4);
      float x[8];
#pragma unroll
      for (int c = 0; c < 4; ++c) { x[c] = va[c] * rc; x[4 + c] = vb[c] * rc; }
#pragma unroll
      for (int c = 0; c < 8; ++c) x[c] = x[c] > 0.f ? x[c] : EXP2(x[c] * LOG2E) - 1.f;
      F16x8 o;
      o.h[0] = pkrtz(x[0], x[1]); o.h[1] = pkrtz(x[2], x[3]);
      o.h[2] = pkrtz(x[4], x[5]); o.h[3] = pkrtz(x[6], x[7]);
      *(f16x8*)(outp + q8 * 8) = o.v;
    }
  }
}

// ---------------- k_out: x = elu(cat@W1 + b1); out = LN(nodes + x)
// 256 blocks x 256 thr: 16 rows/block, 4 waves k-split (256 k each), LDS combine.
__global__ __launch_bounds__(256) void k_out(const _Float16* __restrict__ hcat,
    const _Float16* __restrict__ W1t, const float* __restrict__ b1,
    const float* __restrict__ nodes, const float* __restrict__ gamma,
    const float* __restrict__ beta, float* __restrict__ out) {
  __shared__ __align__(16) float part[4][16][132];
  int t = threadIdx.x, w = t >> 6, l = t & 63, lr = l & 15, lg = l >> 4;
  int ibase = blockIdx.x * 16;
  f32x4 acc[8] = {};
  const _Float16* arow = hcat + (size_t)(ibase + lr) * 1024 + w * 256;
  const _Float16* bb = W1t + w * 256;
#pragma unroll
  for (int ks = 0; ks < 8; ++ks) {
    int k0 = ks * 32 + lg * 8;
    f16x8 A = *(const f16x8*)(arow + k0);
#pragma unroll
    for (int nt = 0; nt < 8; ++nt) {
      f16x8 B = *(const f16x8*)(bb + (nt * 16 + lr) * 1024 + k0);
      acc[nt] = __builtin_amdgcn_mfma_f32_16x16x32_f16(A, B, acc[nt], 0, 0, 0);
    }
  }
#pragma unroll
  for (int nt = 0; nt < 8; ++nt)
#pragma unroll
    for (int r = 0; r < 4; ++r)
      part[w][lg * 4 + r][nt * 16 + lr] = acc[nt][r];
  __syncthreads();
  int row = t >> 4, c16 = t & 15;
  int d0 = c16 * 8;
  size_t gi = (size_t)(ibase + row) * 128;
  f32x4 pa = {}, pb = {};
#pragma unroll
  for (int q = 0; q < 4; ++q) {
    pa += *(const f32x4*)&part[q][row][d0];
    pb += *(const f32x4*)&part[q][row][d0 + 4];
  }
  f32x4 ba = *(const f32x4*)(b1 + d0), bbv = *(const f32x4*)(b1 + d0 + 4);
  f32x4 na = *(const f32x4*)(nodes + gi + d0), nb = *(const f32x4*)(nodes + gi + d0 + 4);
  float y[8];
  float sum = 0.f, sq = 0.f;
#pragma unroll
  for (int c = 0; c < 4; ++c) {
    float x = pa[c] + ba[c];
    x = x > 0.f ? x : EXP2(x * LOG2E) - 1.f;
    y[c] = x + na[c];
    float x2 = pb[c] + bbv[c];
    x2 = x2 > 0.f ? x2 : EXP2(x2 * LOG2E) - 1.f;
    y[4 + c] = x2 + nb[c];
  }
#pragma unroll
  for (int c = 0; c < 8; ++c) { sum += y[c]; sq += y[c] * y[c]; }
#pragma unroll
  for (int off = 1; off < 16; off <<= 1) {
    sum += __shfl_xor(sum, off, 16);
    sq += __shfl_xor(sq, off, 16);
  }
  float mu = sum * (1.f / 128.f);
  float var = sq * (1.f / 128.f) - mu * mu;
  float rs = __builtin_amdgcn_rsqf(var + EPSLN);
  f32x4 ga = *(const f32x4*)(gamma + d0), gb = *(const f32x4*)(gamma + d0 + 4);
  f32x4 bea = *(const f32x4*)(beta + d0), beb = *(const f32x4*)(beta + d0 + 4);
  f32x4 o0, o1;
#pragma unroll
  for (int c = 0; c < 4; ++c) {
    o0[c] = (y[c] - mu) * rs * ga[c] + bea[c];
    o1[c] = (y[4 + c] - mu) * rs * gb[c] + beb[c];
  }
  *(f32x4*)(out + gi + d0) = o0;
  *(f32x4*)(out + gi + d0 + 4) = o1;
}

extern "C" void kernel_launch(void* const* d_in, const int* in_sizes, int n_in,
                              void* d_out, int out_size, void* d_ws, size_t ws_size,
                              hipStream_t stream) {
  const float* nodes = (const float*)d_in[0];
  const int* adj = (const int*)d_in[1];
  const float* W = (const float*)d_in[2];
  const float* a1 = (const float*)d_in[3];
  const float* a2 = (const float*)d_in[4];
  const float* W1 = (const float*)d_in[5];
  const float* b1 = (const float*)d_in[6];
  const float* gamma = (const float*)d_in[7];
  const float* beta = (const float*)d_in[8];
  float* out = (float*)d_out;
  char* ws = (char*)d_ws;

  const size_t OFF_MASK = 0;                       // 2 MB
  const size_t OFF_WHBT = 2097152;                 // 8.4 MB
  const size_t OFF_F1 = OFF_WHBT + 8388608;        // 128 KB
  const size_t OFF_F2 = OFF_F1 + 131072;           // 128 KB
  const size_t OFF_M2 = OFF_F2 + 131072;           // 256 B
  const size_t OFF_E2T = OFF_M2 + 256;             // 256 KB
  const size_t OFF_WT = OFF_E2T + 262144;          // 256 KB
  const size_t OFF_W1T = OFF_WT + 262144;          // 256 KB
  const size_t OFF_HCAT = OFF_W1T + 262144;        // 8.4 MB

  unsigned long long* maskT = (unsigned long long*)(ws + OFF_MASK);
  _Float16* Whbt = (_Float16*)(ws + OFF_WHBT);
  float* f1L = (float*)(ws + OFF_F1);
  float* f2L = (float*)(ws + OFF_F2);
  float* M2L = (float*)(ws + OFF_M2);
  float2* e2t = (float2*)(ws + OFF_E2T);
  _Float16* Wt = (_Float16*)(ws + OFF_WT);
  _Float16* W1t = (_Float16*)(ws + OFF_W1T);
  _Float16* hcat = (_Float16*)(ws + OFF_HCAT);

  k_packprep<<<17408, 256, 0, stream>>>(adj, maskT, W, W1, Wt, W1t);
  k_wh<<<dim3(64, 8), 256, 0, stream>>>(nodes, Wt, a1, a2, Whbt, f1L, f2L);
  k_m2<<<8, 1024, 0, stream>>>(f2L, M2L, e2t);
  k_attn<<<512, 256, 0, stream>>>(Whbt, f1L, M2L, e2t, maskT, hcat);
  k_out<<<256, 256, 0, stream>>>(hcat, W1t, b1, nodes, gamma, beta, out);
}

// Round 6
// 104.073 us; speedup vs baseline: 1.6274x; 1.4725x over previous
//
#include <hip/hip_runtime.h>
#include <hip/hip_bf16.h>

// GAT encoder, N=4096, D=128, H=8.
// k_packprep (adj->bitmask transposed [word][row]; W/W1 -> f16 transposed)
// k_wh   (Wh = nodes@W per head -> Whbt f16 [h][d][n]; f1,f2 (x log2e))
// k_m2   (per-head max M2 of f2L; tables e2t[h][j] = {exp2(f2-M2), exp2(a(f2-M2))})
// k_attn (fused masked-softmax + PV; 64-row blocks, 128-j tiles, global_load_lds
//         DMA staging, double-buffered, ONE barrier/iter; epilogue -> hcat f16)
// k_out  (cat@W1 + b1 with 4-way k-split, elu, +nodes residual, LayerNorm -> f32)

#define NN 4096
#define ALPHA 0.2f
#define EPSLN 1e-5f
#define LOG2E 1.4426950408889634f

typedef __attribute__((ext_vector_type(8))) _Float16 f16x8;
typedef __attribute__((ext_vector_type(4))) _Float16 f16x4;
typedef __attribute__((ext_vector_type(2))) _Float16 f16x2;
typedef __attribute__((ext_vector_type(4))) float f32x4;
typedef __attribute__((ext_vector_type(4))) int i32x4;

union F16x8 { f16x8 v; f16x2 h[4]; };
union F16x4 { f16x4 v; f16x2 h[2]; };

static __device__ inline f16x2 pkrtz(float a, float b) {
  union { decltype(__builtin_amdgcn_cvt_pkrtz(0.f, 0.f)) r; f16x2 h; } u;
  u.r = __builtin_amdgcn_cvt_pkrtz(a, b);
  return u.h;
}

#if __has_builtin(__builtin_amdgcn_exp2f)
#define EXP2(x) __builtin_amdgcn_exp2f(x)
#else
#define EXP2(x) exp2f(x)
#endif

// async global->LDS DMA, 16B per lane. LDS dest is wave-uniform base + lane*16.
static __device__ __forceinline__ void gload16(const void* g, void* l) {
  __builtin_amdgcn_global_load_lds(
      (const __attribute__((address_space(1))) void*)g,
      (__attribute__((address_space(3))) void*)l, 16, 0, 0);
}

static __device__ inline unsigned long long sp4(unsigned long long x) {
  x = (x | (x << 24)) & 0x000000FF000000FFULL;
  x = (x | (x << 12)) & 0x000F000F000F000FULL;
  x = (x | (x << 6))  & 0x0303030303030303ULL;
  x = (x | (x << 3))  & 0x1111111111111111ULL;
  return x;
}

// ---------------- k_packprep: blocks [0,16384): adj -> maskT; rest: W/W1 -> f16^T
__global__ void k_packprep(const int* __restrict__ adj, unsigned long long* __restrict__ maskT,
                           const float* __restrict__ W, const float* __restrict__ W1,
                           _Float16* __restrict__ Wt, _Float16* __restrict__ W1t) {
  int bid = blockIdx.x;
  if (bid < 16384) {
    int wv = threadIdx.x >> 6, l = threadIdx.x & 63;
    int gid = bid * 4 + wv;
    int row = gid >> 4, chunk = gid & 15;
    i32x4 v = *(const i32x4*)(adj + ((size_t)row << 12) + chunk * 256 + l * 4);
    unsigned long long b0 = __ballot(v.x > 0);
    unsigned long long b1 = __ballot(v.y > 0);
    unsigned long long b2 = __ballot(v.z > 0);
    unsigned long long b3 = __ballot(v.w > 0);
    if (l < 4) {
      int sh = l * 16;
      unsigned long long w = sp4((b0 >> sh) & 0xFFFF)
                           | (sp4((b1 >> sh) & 0xFFFF) << 1)
                           | (sp4((b2 >> sh) & 0xFFFF) << 2)
                           | (sp4((b3 >> sh) & 0xFFFF) << 3);
      maskT[(size_t)(chunk * 4 + l) * NN + row] = w;
    }
  } else {
    int idx = (bid - 16384) * 256 + threadIdx.x;
    if (idx < 131072) {
      int h = idx >> 14, r = idx & 16383, d = r >> 7, e = r & 127;
      Wt[h * 16384 + e * 128 + d] = (_Float16)W[idx];
    } else {
      int j = idx - 131072;
      int k = j >> 7, d = j & 127;
      W1t[d * 1024 + k] = (_Float16)W1[j];
    }
  }
}

// ---------------- k_wh: per head GEMM [4096x128]@[128x128] + f1/f2 dots
__global__ __launch_bounds__(256) void k_wh(const float* __restrict__ nodes,
    const _Float16* __restrict__ Wt, const float* __restrict__ a1,
    const float* __restrict__ a2, _Float16* __restrict__ Whbt,
    float* __restrict__ f1L, float* __restrict__ f2L) {
  int h = blockIdx.y;
  int wv = threadIdx.x >> 6, l = threadIdx.x & 63;
  int lr = l & 15, lg = l >> 4;
  int ibase = blockIdx.x * 64 + wv * 16;
  f32x4 acc[8] = {};
  const float* arow = nodes + (size_t)(ibase + lr) * 128;
  const _Float16* bbase = Wt + h * 16384;
#pragma unroll
  for (int ks = 0; ks < 4; ++ks) {
    int k0 = ks * 32 + lg * 8;
    f32x4 av0 = *(const f32x4*)(arow + k0);
    f32x4 av1 = *(const f32x4*)(arow + k0 + 4);
    F16x8 A;
    A.h[0] = pkrtz(av0[0], av0[1]);
    A.h[1] = pkrtz(av0[2], av0[3]);
    A.h[2] = pkrtz(av1[0], av1[1]);
    A.h[3] = pkrtz(av1[2], av1[3]);
#pragma unroll
    for (int nt = 0; nt < 8; ++nt) {
      f16x8 B = *(const f16x8*)(bbase + (nt * 16 + lr) * 128 + k0);
      acc[nt] = __builtin_amdgcn_mfma_f32_16x16x32_f16(A.v, B, acc[nt], 0, 0, 0);
    }
  }
#pragma unroll
  for (int nt = 0; nt < 8; ++nt) {
    F16x4 o;
    o.h[0] = pkrtz(acc[nt][0], acc[nt][1]);
    o.h[1] = pkrtz(acc[nt][2], acc[nt][3]);
    *(f16x4*)(Whbt + (size_t)(h * 128 + nt * 16 + lr) * NN + ibase + lg * 4) = o.v;
  }
  float a1r[8], a2r[8];
#pragma unroll
  for (int nt = 0; nt < 8; ++nt) {
    a1r[nt] = a1[h * 128 + nt * 16 + lr];
    a2r[nt] = a2[h * 128 + nt * 16 + lr];
  }
#pragma unroll
  for (int r = 0; r < 4; ++r) {
    float s1 = 0.f, s2 = 0.f;
#pragma unroll
    for (int nt = 0; nt < 8; ++nt) { s1 += acc[nt][r] * a1r[nt]; s2 += acc[nt][r] * a2r[nt]; }
    s1 += __shfl_xor(s1, 1, 16); s1 += __shfl_xor(s1, 2, 16);
    s1 += __shfl_xor(s1, 4, 16); s1 += __shfl_xor(s1, 8, 16);
    s2 += __shfl_xor(s2, 1, 16); s2 += __shfl_xor(s2, 2, 16);
    s2 += __shfl_xor(s2, 4, 16); s2 += __shfl_xor(s2, 8, 16);
    if (lr == 0) {
      int i = ibase + lg * 4 + r;
      f1L[h * NN + i] = s1 * LOG2E;
      f2L[h * NN + i] = s2 * LOG2E;
    }
  }
}

// ---------------- k_m2: per-head max of f2L + scaled exp tables (factors <= 1)
__global__ __launch_bounds__(1024) void k_m2(const float* __restrict__ f2L,
    float* __restrict__ M2L, float2* __restrict__ e2t) {
  __shared__ float red[16];
  int h = blockIdx.x, t = threadIdx.x;
  float a[4];
#pragma unroll
  for (int i = 0; i < 4; ++i) a[i] = f2L[h * NN + t + i * 1024];
  float v = fmaxf(fmaxf(a[0], a[1]), fmaxf(a[2], a[3]));
#pragma unroll
  for (int off = 1; off < 64; off <<= 1) v = fmaxf(v, __shfl_xor(v, off, 64));
  if ((t & 63) == 0) red[t >> 6] = v;
  __syncthreads();
  if (t < 16) {
    float m = red[t];
#pragma unroll
    for (int off = 1; off < 16; off <<= 1) m = fmaxf(m, __shfl_xor(m, off, 16));
    if (t == 0) { red[0] = m; M2L[h] = m; }
  }
  __syncthreads();
  float M2 = red[0];
#pragma unroll
  for (int i = 0; i < 4; ++i) {
    float d = a[i] - M2;
    float2 e; e.x = EXP2(d); e.y = EXP2(ALPHA * d);
    e2t[h * NN + t + i * 1024] = e;
  }
}

// ---------------- k_attn
// grid 512 (1D): h = bid&7 (XCD-local heads), rowtile = bid>>3 (64 rows).
// 4 waves: rh = w>>1 (32-row half), jh = w&1 (64-j half of the 128-j tile).
// 32 tiles, ONE barrier each. B tile [128 d][128 j] f16 = 32KB x2 (dbuf),
// staged via global_load_lds with read-swizzle pre-applied to the GLOBAL
// source address (LDS dest linear). Read swizzle: slot ^= (d&15), 16B slots.
// p = max(E1'*e2', Ea'*e2a') masked; factors <= 1 (single-pass softmax).
// Epilogue: jh-combine in LDS (reuses Bt), /den + elu -> hcat f16.
__global__ __launch_bounds__(256, 2) void k_attn(const _Float16* __restrict__ Whbt,
    const float* __restrict__ f1L, const float* __restrict__ M2L,
    const float2* __restrict__ e2t, const unsigned long long* __restrict__ maskT,
    _Float16* __restrict__ hcat) {
  __shared__ __align__(16) char Bt[2][32768];
  __shared__ float denL[64];
  int t = threadIdx.x, w = t >> 6, l = t & 63, lr = l & 15, lg = l >> 4;
  int bid = blockIdx.x;
  int h = bid & 7;
  int rowbase = (bid >> 3) * 64;
  int rh = w >> 1, jh = w & 1;
  int r0 = rowbase + rh * 32 + lr, r1 = r0 + 16;
  float f10 = f1L[h * NN + r0], f11 = f1L[h * NN + r1];
  float M2 = M2L[h];
  float s0 = f10 + M2, s1 = f11 + M2;
  float mL0 = fmaxf(s0, ALPHA * s0), mL1 = fmaxf(s1, ALPHA * s1);
  float E10 = EXP2(s0 - mL0), Ea0 = EXP2(ALPHA * s0 - mL0);
  float E11 = EXP2(s1 - mL1), Ea1 = EXP2(ALPHA * s1 - mL1);
  f32x4 acc0[8] = {}, acc1[8] = {};
  float den0 = 0.f, den1 = 0.f;
  const _Float16* src = Whbt + ((size_t)h << 19);
  const float* ep = (const float*)(e2t + (size_t)h * NN);

  // staging geometry: thread t, pass p writes LDS linear [p*4096 + t*16].
  // That slot is row d = p*16 + (t>>4), 16B slot (t&15). Read XORs slot with
  // (d&15) = (t>>4)&15, so source j-chunk jc = (t&15) ^ ((t>>4)&15).
  int t4 = t >> 4;
  int jc = (t & 15) ^ (t4 & 15);
  size_t goff = (size_t)t4 * NN + jc * 8;

  // prologue: DMA tile 0 into buf 0
  {
    const _Float16* gp = src + goff;
    char* lb = &Bt[0][0] + t * 16;
#pragma unroll
    for (int p = 0; p < 8; ++p)
      gload16(gp + (size_t)p * 16 * NN, lb + p * 4096);
  }
  __syncthreads();

  for (int ct = 0; ct < 32; ++ct) {
    // issue next tile's DMA (drained by this iteration's end barrier)
    if (ct + 1 < 32) {
      const _Float16* gp = src + goff + (ct + 1) * 128;
      char* lb = &Bt[(ct + 1) & 1][0] + t * 16;
#pragma unroll
      for (int p = 0; p < 8; ++p)
        gload16(gp + (size_t)p * 16 * NN, lb + p * 4096);
    }
    unsigned long long m0 = maskT[(size_t)(ct * 2 + jh) * NN + r0];
    unsigned long long m1 = maskT[(size_t)(ct * 2 + jh) * NN + r1];
    const char* btr = &Bt[ct & 1][0];
    const float* eq = ep + (ct * 128 + jh * 64) * 2;
#pragma unroll
    for (int ks = 0; ks < 2; ++ks) {
      const float* e2p = eq + (ks * 32 + lg * 8) * 2;
      f32x4 Q[4];
#pragma unroll
      for (int c = 0; c < 4; ++c) Q[c] = *(const f32x4*)(e2p + c * 4);
      int sh = ks * 32 + lg * 8;
      unsigned bits0 = (unsigned)(m0 >> sh);
      unsigned bits1 = (unsigned)(m1 >> sh);
      float p0[8], p1[8];
#pragma unroll
      for (int e = 0; e < 8; ++e) {
        float e2 = Q[e >> 1][(e & 1) * 2];
        float e2a = Q[e >> 1][(e & 1) * 2 + 1];
        float v0 = fmaxf(E10 * e2, Ea0 * e2a);
        p0[e] = ((bits0 >> e) & 1) ? v0 : 0.f;
        den0 += p0[e];
        float v1 = fmaxf(E11 * e2, Ea1 * e2a);
        p1[e] = ((bits1 >> e) & 1) ? v1 : 0.f;
        den1 += p1[e];
      }
      F16x8 A0, A1;
#pragma unroll
      for (int qq = 0; qq < 4; ++qq) {
        A0.h[qq] = pkrtz(p0[2 * qq], p0[2 * qq + 1]);
        A1.h[qq] = pkrtz(p1[2 * qq], p1[2 * qq + 1]);
      }
      int slotbase = jh * 8 + ks * 4 + lg;
#pragma unroll
      for (int nt = 0; nt < 8; ++nt) {
        int d = nt * 16 + lr;
        int byteoff = d * 256 + ((slotbase ^ lr) << 4);
        f16x8 B = *(const f16x8*)(btr + byteoff);
        acc0[nt] = __builtin_amdgcn_mfma_f32_16x16x32_f16(A0.v, B, acc0[nt], 0, 0, 0);
        acc1[nt] = __builtin_amdgcn_mfma_f32_16x16x32_f16(A1.v, B, acc1[nt], 0, 0, 0);
      }
    }
    __syncthreads();  // drains next-tile DMA; orders buffer reuse
  }
  den0 += __shfl_xor(den0, 16, 64); den0 += __shfl_xor(den0, 32, 64);
  den1 += __shfl_xor(den1, 16, 64); den1 += __shfl_xor(den1, 32, 64);

  // combine j-halves in LDS (reuses Bt; loop-end barrier protects reads)
  float* reg = (float*)Bt + (size_t)rh * 32 * 132;
  if (jh == 0) {
#pragma unroll
    for (int nt = 0; nt < 8; ++nt)
#pragma unroll
      for (int r = 0; r < 4; ++r) {
        reg[(lg * 4 + r) * 132 + nt * 16 + lr] = acc0[nt][r];
        reg[(16 + lg * 4 + r) * 132 + nt * 16 + lr] = acc1[nt][r];
      }
    if (l < 16) { denL[rh * 32 + lr] = den0; denL[rh * 32 + 16 + lr] = den1; }
  }
  __syncthreads();
  if (jh == 1) {
#pragma unroll
    for (int nt = 0; nt < 8; ++nt)
#pragma unroll
      for (int r = 0; r < 4; ++r) {
        reg[(lg * 4 + r) * 132 + nt * 16 + lr] += acc0[nt][r];
        reg[(16 + lg * 4 + r) * 132 + nt * 16 + lr] += acc1[nt][r];
      }
    if (l < 16) { denL[rh * 32 + lr] += den0; denL[rh * 32 + 16 + lr] += den1; }
  }
  __syncthreads();
  {
    int row = t >> 2, seg = t & 3;
    const float* rg = (float*)Bt + (size_t)(row >> 5) * 32 * 132 + (row & 31) * 132 + seg * 32;
    float rc = __builtin_amdgcn_rcpf(denL[row]);
    _Float16* outp = hcat + (size_t)(rowbase + row) * 1024 + h * 128 + seg * 32;
#pragma unroll
    for (int q8 = 0; q8 < 4; ++q8) {
      f32x4 va = *(const f32x4*)(rg + q8 * 8);
      f32x4 vb = *(const f32x4*)(rg + q8 * 8 + 4);
      float x[8];
#pragma unroll
      for (int c = 0; c < 4; ++c) { x[c] = va[c] * rc; x[4 + c] = vb[c] * rc; }
#pragma unroll
      for (int c = 0; c < 8; ++c) x[c] = x[c] > 0.f ? x[c] : EXP2(x[c] * LOG2E) - 1.f;
      F16x8 o;
      o.h[0] = pkrtz(x[0], x[1]); o.h[1] = pkrtz(x[2], x[3]);
      o.h[2] = pkrtz(x[4], x[5]); o.h[3] = pkrtz(x[6], x[7]);
      *(f16x8*)(outp + q8 * 8) = o.v;
    }
  }
}

// ---------------- k_out: x = elu(cat@W1 + b1); out = LN(nodes + x)
// 256 blocks x 256 thr: 16 rows/block, 4 waves k-split (256 k each), LDS combine.
__global__ __launch_bounds__(256) void k_out(const _Float16* __restrict__ hcat,
    const _Float16* __restrict__ W1t, const float* __restrict__ b1,
    const float* __restrict__ nodes, const float* __restrict__ gamma,
    const float* __restrict__ beta, float* __restrict__ out) {
  __shared__ __align__(16) float part[4][16][132];
  int t = threadIdx.x, w = t >> 6, l = t & 63, lr = l & 15, lg = l >> 4;
  int ibase = blockIdx.x * 16;
  f32x4 acc[8] = {};
  const _Float16* arow = hcat + (size_t)(ibase + lr) * 1024 + w * 256;
  const _Float16* bb = W1t + w * 256;
#pragma unroll
  for (int ks = 0; ks < 8; ++ks) {
    int k0 = ks * 32 + lg * 8;
    f16x8 A = *(const f16x8*)(arow + k0);
#pragma unroll
    for (int nt = 0; nt < 8; ++nt) {
      f16x8 B = *(const f16x8*)(bb + (nt * 16 + lr) * 1024 + k0);
      acc[nt] = __builtin_amdgcn_mfma_f32_16x16x32_f16(A, B, acc[nt], 0, 0, 0);
    }
  }
#pragma unroll
  for (int nt = 0; nt < 8; ++nt)
#pragma unroll
    for (int r = 0; r < 4; ++r)
      part[w][lg * 4 + r][nt * 16 + lr] = acc[nt][r];
  __syncthreads();
  int row = t >> 4, c16 = t & 15;
  int d0 = c16 * 8;
  size_t gi = (size_t)(ibase + row) * 128;
  f32x4 pa = {}, pb = {};
#pragma unroll
  for (int q = 0; q < 4; ++q) {
    pa += *(const f32x4*)&part[q][row][d0];
    pb += *(const f32x4*)&part[q][row][d0 + 4];
  }
  f32x4 ba = *(const f32x4*)(b1 + d0), bbv = *(const f32x4*)(b1 + d0 + 4);
  f32x4 na = *(const f32x4*)(nodes + gi + d0), nb = *(const f32x4*)(nodes + gi + d0 + 4);
  float y[8];
  float sum = 0.f, sq = 0.f;
#pragma unroll
  for (int c = 0; c < 4; ++c) {
    float x = pa[c] + ba[c];
    x = x > 0.f ? x : EXP2(x * LOG2E) - 1.f;
    y[c] = x + na[c];
    float x2 = pb[c] + bbv[c];
    x2 = x2 > 0.f ? x2 : EXP2(x2 * LOG2E) - 1.f;
    y[4 + c] = x2 + nb[c];
  }
#pragma unroll
  for (int c = 0; c < 8; ++c) { sum += y[c]; sq += y[c] * y[c]; }
#pragma unroll
  for (int off = 1; off < 16; off <<= 1) {
    sum += __shfl_xor(sum, off, 16);
    sq += __shfl_xor(sq, off, 16);
  }
  float mu = sum * (1.f / 128.f);
  float var = sq * (1.f / 128.f) - mu * mu;
  float rs = __builtin_amdgcn_rsqf(var + EPSLN);
  f32x4 ga = *(const f32x4*)(gamma + d0), gb = *(const f32x4*)(gamma + d0 + 4);
  f32x4 bea = *(const f32x4*)(beta + d0), beb = *(const f32x4*)(beta + d0 + 4);
  f32x4 o0, o1;
#pragma unroll
  for (int c = 0; c < 4; ++c) {
    o0[c] = (y[c] - mu) * rs * ga[c] + bea[c];
    o1[c] = (y[4 + c] - mu) * rs * gb[c] + beb[c];
  }
  *(f32x4*)(out + gi + d0) = o0;
  *(f32x4*)(out + gi + d0 + 4) = o1;
}

extern "C" void kernel_launch(void* const* d_in, const int* in_sizes, int n_in,
                              void* d_out, int out_size, void* d_ws, size_t ws_size,
                              hipStream_t stream) {
  const float* nodes = (const float*)d_in[0];
  const int* adj = (const int*)d_in[1];
  const float* W = (const float*)d_in[2];
  const float* a1 = (const float*)d_in[3];
  const float* a2 = (const float*)d_in[4];
  const float* W1 = (const float*)d_in[5];
  const float* b1 = (const float*)d_in[6];
  const float* gamma = (const float*)d_in[7];
  const float* beta = (const float*)d_in[8];
  float* out = (float*)d_out;
  char* ws = (char*)d_ws;

  const size_t OFF_MASK = 0;                       // 2 MB
  const size_t OFF_WHBT = 2097152;                 // 8.4 MB
  const size_t OFF_F1 = OFF_WHBT + 8388608;        // 128 KB
  const size_t OFF_F2 = OFF_F1 + 131072;           // 128 KB
  const size_t OFF_M2 = OFF_F2 + 131072;           // 256 B
  const size_t OFF_E2T = OFF_M2 + 256;             // 256 KB
  const size_t OFF_WT = OFF_E2T + 262144;          // 256 KB
  const size_t OFF_W1T = OFF_WT + 262144;          // 256 KB
  const size_t OFF_HCAT = OFF_W1T + 262144;        // 8.4 MB

  unsigned long long* maskT = (unsigned long long*)(ws + OFF_MASK);
  _Float16* Whbt = (_Float16*)(ws + OFF_WHBT);
  float* f1L = (float*)(ws + OFF_F1);
  float* f2L = (float*)(ws + OFF_F2);
  float* M2L = (float*)(ws + OFF_M2);
  float2* e2t = (float2*)(ws + OFF_E2T);
  _Float16* Wt = (_Float16*)(ws + OFF_WT);
  _Float16* W1t = (_Float16*)(ws + OFF_W1T);
  _Float16* hcat = (_Float16*)(ws + OFF_HCAT);

  k_packprep<<<17408, 256, 0, stream>>>(adj, maskT, W, W1, Wt, W1t);
  k_wh<<<dim3(64, 8), 256, 0, stream>>>(nodes, Wt, a1, a2, Whbt, f1L, f2L);
  k_m2<<<8, 1024, 0, stream>>>(f2L, M2L, e2t);
  k_attn<<<512, 256, 0, stream>>>(Whbt, f1L, M2L, e2t, maskT, hcat);
  k_out<<<256, 256, 0, stream>>>(hcat, W1t, b1, nodes, gamma, beta, out);
}

// Round 7
// 99.019 us; speedup vs baseline: 1.7105x; 1.0510x over previous
//
#include <hip/hip_runtime.h>
#include <hip/hip_bf16.h>

// GAT encoder, N=4096, D=128, H=8.
// k_packprep (adj->bitmask transposed [word][row]; W/W1 -> f16 transposed)
// k_wh   (Wh = nodes@W per head -> Whbt f16 [h][d][n]; f1,f2 (x log2e))
// k_m2   (per-head max M2 of f2L; tables e2t[h][j] = {exp2(f2-M2), exp2(a(f2-M2))})
// k_attn (fused masked-softmax + PV; 64-row blocks, 128-j tiles, global_load_lds
//         DMA staging of B-tile AND e2-tile, dbuf, ONE barrier/iter, masks
//         prefetched 1 iter ahead in regs -> no same-iter global consumption)
// k_out  (cat@W1 + b1 with 4-way k-split, elu, +nodes residual, LayerNorm -> f32)

#define NN 4096
#define ALPHA 0.2f
#define EPSLN 1e-5f
#define LOG2E 1.4426950408889634f

typedef __attribute__((ext_vector_type(8))) _Float16 f16x8;
typedef __attribute__((ext_vector_type(4))) _Float16 f16x4;
typedef __attribute__((ext_vector_type(2))) _Float16 f16x2;
typedef __attribute__((ext_vector_type(4))) float f32x4;
typedef __attribute__((ext_vector_type(4))) int i32x4;

union F16x8 { f16x8 v; f16x2 h[4]; };
union F16x4 { f16x4 v; f16x2 h[2]; };

static __device__ inline f16x2 pkrtz(float a, float b) {
  union { decltype(__builtin_amdgcn_cvt_pkrtz(0.f, 0.f)) r; f16x2 h; } u;
  u.r = __builtin_amdgcn_cvt_pkrtz(a, b);
  return u.h;
}

#if __has_builtin(__builtin_amdgcn_exp2f)
#define EXP2(x) __builtin_amdgcn_exp2f(x)
#else
#define EXP2(x) exp2f(x)
#endif

// async global->LDS DMA, 16B per lane. LDS dest is wave-uniform base + lane*16.
static __device__ __forceinline__ void gload16(const void* g, void* l) {
  __builtin_amdgcn_global_load_lds(
      (const __attribute__((address_space(1))) void*)g,
      (__attribute__((address_space(3))) void*)l, 16, 0, 0);
}

static __device__ inline unsigned long long sp4(unsigned long long x) {
  x = (x | (x << 24)) & 0x000000FF000000FFULL;
  x = (x | (x << 12)) & 0x000F000F000F000FULL;
  x = (x | (x << 6))  & 0x0303030303030303ULL;
  x = (x | (x << 3))  & 0x1111111111111111ULL;
  return x;
}

// ---------------- k_packprep: blocks [0,16384): adj -> maskT; rest: W/W1 -> f16^T
__global__ void k_packprep(const int* __restrict__ adj, unsigned long long* __restrict__ maskT,
                           const float* __restrict__ W, const float* __restrict__ W1,
                           _Float16* __restrict__ Wt, _Float16* __restrict__ W1t) {
  int bid = blockIdx.x;
  if (bid < 16384) {
    int wv = threadIdx.x >> 6, l = threadIdx.x & 63;
    int gid = bid * 4 + wv;
    int row = gid >> 4, chunk = gid & 15;
    i32x4 v = *(const i32x4*)(adj + ((size_t)row << 12) + chunk * 256 + l * 4);
    unsigned long long b0 = __ballot(v.x > 0);
    unsigned long long b1 = __ballot(v.y > 0);
    unsigned long long b2 = __ballot(v.z > 0);
    unsigned long long b3 = __ballot(v.w > 0);
    if (l < 4) {
      int sh = l * 16;
      unsigned long long w = sp4((b0 >> sh) & 0xFFFF)
                           | (sp4((b1 >> sh) & 0xFFFF) << 1)
                           | (sp4((b2 >> sh) & 0xFFFF) << 2)
                           | (sp4((b3 >> sh) & 0xFFFF) << 3);
      maskT[(size_t)(chunk * 4 + l) * NN + row] = w;
    }
  } else {
    int idx = (bid - 16384) * 256 + threadIdx.x;
    if (idx < 131072) {
      int h = idx >> 14, r = idx & 16383, d = r >> 7, e = r & 127;
      Wt[h * 16384 + e * 128 + d] = (_Float16)W[idx];
    } else {
      int j = idx - 131072;
      int k = j >> 7, d = j & 127;
      W1t[d * 1024 + k] = (_Float16)W1[j];
    }
  }
}

// ---------------- k_wh: per head GEMM [4096x128]@[128x128] + f1/f2 dots
__global__ __launch_bounds__(256) void k_wh(const float* __restrict__ nodes,
    const _Float16* __restrict__ Wt, const float* __restrict__ a1,
    const float* __restrict__ a2, _Float16* __restrict__ Whbt,
    float* __restrict__ f1L, float* __restrict__ f2L) {
  int h = blockIdx.y;
  int wv = threadIdx.x >> 6, l = threadIdx.x & 63;
  int lr = l & 15, lg = l >> 4;
  int ibase = blockIdx.x * 64 + wv * 16;
  f32x4 acc[8] = {};
  const float* arow = nodes + (size_t)(ibase + lr) * 128;
  const _Float16* bbase = Wt + h * 16384;
#pragma unroll
  for (int ks = 0; ks < 4; ++ks) {
    int k0 = ks * 32 + lg * 8;
    f32x4 av0 = *(const f32x4*)(arow + k0);
    f32x4 av1 = *(const f32x4*)(arow + k0 + 4);
    F16x8 A;
    A.h[0] = pkrtz(av0[0], av0[1]);
    A.h[1] = pkrtz(av0[2], av0[3]);
    A.h[2] = pkrtz(av1[0], av1[1]);
    A.h[3] = pkrtz(av1[2], av1[3]);
#pragma unroll
    for (int nt = 0; nt < 8; ++nt) {
      f16x8 B = *(const f16x8*)(bbase + (nt * 16 + lr) * 128 + k0);
      acc[nt] = __builtin_amdgcn_mfma_f32_16x16x32_f16(A.v, B, acc[nt], 0, 0, 0);
    }
  }
#pragma unroll
  for (int nt = 0; nt < 8; ++nt) {
    F16x4 o;
    o.h[0] = pkrtz(acc[nt][0], acc[nt][1]);
    o.h[1] = pkrtz(acc[nt][2], acc[nt][3]);
    *(f16x4*)(Whbt + (size_t)(h * 128 + nt * 16 + lr) * NN + ibase + lg * 4) = o.v;
  }
  float a1r[8], a2r[8];
#pragma unroll
  for (int nt = 0; nt < 8; ++nt) {
    a1r[nt] = a1[h * 128 + nt * 16 + lr];
    a2r[nt] = a2[h * 128 + nt * 16 + lr];
  }
#pragma unroll
  for (int r = 0; r < 4; ++r) {
    float s1 = 0.f, s2 = 0.f;
#pragma unroll
    for (int nt = 0; nt < 8; ++nt) { s1 += acc[nt][r] * a1r[nt]; s2 += acc[nt][r] * a2r[nt]; }
    s1 += __shfl_xor(s1, 1, 16); s1 += __shfl_xor(s1, 2, 16);
    s1 += __shfl_xor(s1, 4, 16); s1 += __shfl_xor(s1, 8, 16);
    s2 += __shfl_xor(s2, 1, 16); s2 += __shfl_xor(s2, 2, 16);
    s2 += __shfl_xor(s2, 4, 16); s2 += __shfl_xor(s2, 8, 16);
    if (lr == 0) {
      int i = ibase + lg * 4 + r;
      f1L[h * NN + i] = s1 * LOG2E;
      f2L[h * NN + i] = s2 * LOG2E;
    }
  }
}

// ---------------- k_m2: per-head max of f2L + scaled exp tables (factors <= 1)
__global__ __launch_bounds__(1024) void k_m2(const float* __restrict__ f2L,
    float* __restrict__ M2L, float2* __restrict__ e2t) {
  __shared__ float red[16];
  int h = blockIdx.x, t = threadIdx.x;
  float a[4];
#pragma unroll
  for (int i = 0; i < 4; ++i) a[i] = f2L[h * NN + t + i * 1024];
  float v = fmaxf(fmaxf(a[0], a[1]), fmaxf(a[2], a[3]));
#pragma unroll
  for (int off = 1; off < 64; off <<= 1) v = fmaxf(v, __shfl_xor(v, off, 64));
  if ((t & 63) == 0) red[t >> 6] = v;
  __syncthreads();
  if (t < 16) {
    float m = red[t];
#pragma unroll
    for (int off = 1; off < 16; off <<= 1) m = fmaxf(m, __shfl_xor(m, off, 16));
    if (t == 0) { red[0] = m; M2L[h] = m; }
  }
  __syncthreads();
  float M2 = red[0];
#pragma unroll
  for (int i = 0; i < 4; ++i) {
    float d = a[i] - M2;
    float2 e; e.x = EXP2(d); e.y = EXP2(ALPHA * d);
    e2t[h * NN + t + i * 1024] = e;
  }
}

// ---------------- k_attn
// grid 512 (1D): h = bid&7 (XCD-local heads), rowtile = bid>>3 (64 rows).
// 4 waves: rh = w>>1 (32-row half), jh = w&1 (64-j half of the 128-j tile).
// 32 tiles, ONE barrier each. Per tile DMA: B [128d][128j] f16 32KB (swizzled
// via pre-swizzled global source) + e2 pairs 1KB -> LDS (dbuf both).
// Masks prefetched one iteration ahead into regs. NO global load is consumed
// in the iteration that issues it: only the pre-barrier vmcnt(0) drain touches
// global latency, and it has the whole compute phase to complete.
// p = max(E1'*e2', Ea'*e2a') masked; factors <= 1 (single-pass softmax).
// Epilogue: jh-combine in LDS (reuses Bt), /den + elu -> hcat f16.
__global__ __launch_bounds__(256, 2) void k_attn(const _Float16* __restrict__ Whbt,
    const float* __restrict__ f1L, const float* __restrict__ M2L,
    const float2* __restrict__ e2t, const unsigned long long* __restrict__ maskT,
    _Float16* __restrict__ hcat) {
  __shared__ __align__(16) char Bt[2][32768];
  __shared__ __align__(16) float e2s[2][256];
  __shared__ float denL[64];
  int t = threadIdx.x, w = t >> 6, l = t & 63, lr = l & 15, lg = l >> 4;
  int bid = blockIdx.x;
  int h = bid & 7;
  int rowbase = (bid >> 3) * 64;
  int rh = w >> 1, jh = w & 1;
  int r0 = rowbase + rh * 32 + lr, r1 = r0 + 16;
  float f10 = f1L[h * NN + r0], f11 = f1L[h * NN + r1];
  float M2 = M2L[h];
  float s0 = f10 + M2, s1 = f11 + M2;
  float mL0 = fmaxf(s0, ALPHA * s0), mL1 = fmaxf(s1, ALPHA * s1);
  float E10 = EXP2(s0 - mL0), Ea0 = EXP2(ALPHA * s0 - mL0);
  float E11 = EXP2(s1 - mL1), Ea1 = EXP2(ALPHA * s1 - mL1);
  f32x4 acc0[8] = {}, acc1[8] = {};
  float den0 = 0.f, den1 = 0.f;
  const _Float16* src = Whbt + ((size_t)h << 19);
  const float* ep = (const float*)(e2t + (size_t)h * NN);

  // staging geometry: thread t, pass p writes LDS linear [p*4096 + t*16].
  // That slot is row d = p*16 + (t>>4), 16B slot (t&15). Read XORs slot with
  // (d&15) = (t>>4)&15, so source j-chunk jc = (t&15) ^ ((t>>4)&15).
  int t4 = t >> 4;
  int jc = (t & 15) ^ (t4 & 15);
  size_t goff = (size_t)t4 * NN + jc * 8;

  // prologue: DMA tile 0 (B + e2) into buf 0; masks for iter 0 into regs
  {
    const _Float16* gp = src + goff;
    char* lb = &Bt[0][0] + t * 16;
#pragma unroll
    for (int p = 0; p < 8; ++p)
      gload16(gp + (size_t)p * 16 * NN, lb + p * 4096);
    if (t < 64) gload16(ep + t * 4, (char*)&e2s[0][0] + t * 16);
  }
  unsigned long long m0 = maskT[(size_t)jh * NN + r0];
  unsigned long long m1 = maskT[(size_t)jh * NN + r1];
  __syncthreads();

  for (int ct = 0; ct < 32; ++ct) {
    // prefetch next masks (regs) then issue next tile's DMA (LDS)
    unsigned long long m0n = 0, m1n = 0;
    if (ct + 1 < 32) {
      m0n = maskT[(size_t)((ct + 1) * 2 + jh) * NN + r0];
      m1n = maskT[(size_t)((ct + 1) * 2 + jh) * NN + r1];
      const _Float16* gp = src + goff + (ct + 1) * 128;
      char* lb = &Bt[(ct + 1) & 1][0] + t * 16;
#pragma unroll
      for (int p = 0; p < 8; ++p)
        gload16(gp + (size_t)p * 16 * NN, lb + p * 4096);
      if (t < 64) gload16(ep + (ct + 1) * 256 + t * 4, (char*)&e2s[(ct + 1) & 1][0] + t * 16);
    }
    const char* btr = &Bt[ct & 1][0];
    const float* eq = &e2s[ct & 1][jh * 128];
#pragma unroll
    for (int ks = 0; ks < 2; ++ks) {
      const float* e2p = eq + (ks * 32 + lg * 8) * 2;
      f32x4 Q[4];
#pragma unroll
      for (int c = 0; c < 4; ++c) Q[c] = *(const f32x4*)(e2p + c * 4);
      int sh = ks * 32 + lg * 8;
      unsigned bits0 = (unsigned)(m0 >> sh);
      unsigned bits1 = (unsigned)(m1 >> sh);
      float p0[8], p1[8];
#pragma unroll
      for (int e = 0; e < 8; ++e) {
        float e2 = Q[e >> 1][(e & 1) * 2];
        float e2a = Q[e >> 1][(e & 1) * 2 + 1];
        float v0 = fmaxf(E10 * e2, Ea0 * e2a);
        p0[e] = ((bits0 >> e) & 1) ? v0 : 0.f;
        den0 += p0[e];
        float v1 = fmaxf(E11 * e2, Ea1 * e2a);
        p1[e] = ((bits1 >> e) & 1) ? v1 : 0.f;
        den1 += p1[e];
      }
      F16x8 A0, A1;
#pragma unroll
      for (int qq = 0; qq < 4; ++qq) {
        A0.h[qq] = pkrtz(p0[2 * qq], p0[2 * qq + 1]);
        A1.h[qq] = pkrtz(p1[2 * qq], p1[2 * qq + 1]);
      }
      int slotbase = jh * 8 + ks * 4 + lg;
      __builtin_amdgcn_s_setprio(1);
#pragma unroll
      for (int nt = 0; nt < 8; ++nt) {
        int d = nt * 16 + lr;
        int byteoff = d * 256 + ((slotbase ^ lr) << 4);
        f16x8 B = *(const f16x8*)(btr + byteoff);
        acc0[nt] = __builtin_amdgcn_mfma_f32_16x16x32_f16(A0.v, B, acc0[nt], 0, 0, 0);
        acc1[nt] = __builtin_amdgcn_mfma_f32_16x16x32_f16(A1.v, B, acc1[nt], 0, 0, 0);
      }
      __builtin_amdgcn_s_setprio(0);
    }
    __syncthreads();  // drains next-tile DMA; orders buffer reuse
    if (ct + 1 < 32) { m0 = m0n; m1 = m1n; }
  }
  den0 += __shfl_xor(den0, 16, 64); den0 += __shfl_xor(den0, 32, 64);
  den1 += __shfl_xor(den1, 16, 64); den1 += __shfl_xor(den1, 32, 64);

  // combine j-halves in LDS (reuses Bt; loop-end barrier protects reads)
  float* reg = (float*)Bt + (size_t)rh * 32 * 132;
  if (jh == 0) {
#pragma unroll
    for (int nt = 0; nt < 8; ++nt)
#pragma unroll
      for (int r = 0; r < 4; ++r) {
        reg[(lg * 4 + r) * 132 + nt * 16 + lr] = acc0[nt][r];
        reg[(16 + lg * 4 + r) * 132 + nt * 16 + lr] = acc1[nt][r];
      }
    if (l < 16) { denL[rh * 32 + lr] = den0; denL[rh * 32 + 16 + lr] = den1; }
  }
  __syncthreads();
  if (jh == 1) {
#pragma unroll
    for (int nt = 0; nt < 8; ++nt)
#pragma unroll
      for (int r = 0; r < 4; ++r) {
        reg[(lg * 4 + r) * 132 + nt * 16 + lr] += acc0[nt][r];
        reg[(16 + lg * 4 + r) * 132 + nt * 16 + lr] += acc1[nt][r];
      }
    if (l < 16) { denL[rh * 32 + lr] += den0; denL[rh * 32 + 16 + lr] += den1; }
  }
  __syncthreads();
  {
    int row = t >> 2, seg = t & 3;
    const float* rg = (float*)Bt + (size_t)(row >> 5) * 32 * 132 + (row & 31) * 132 + seg * 32;
    float rc = __builtin_amdgcn_rcpf(denL[row]);
    _Float16* outp = hcat + (size_t)(rowbase + row) * 1024 + h * 128 + seg * 32;
#pragma unroll
    for (int q8 = 0; q8 < 4; ++q8) {
      f32x4 va = *(const f32x4*)(rg + q8 * 8);
      f32x4 vb = *(const f32x4*)(rg + q8 * 8 + 4);
      float x[8];
#pragma unroll
      for (int c = 0; c < 4; ++c) { x[c] = va[c] * rc; x[4 + c] = vb[c] * rc; }
#pragma unroll
      for (int c = 0; c < 8; ++c) x[c] = x[c] > 0.f ? x[c] : EXP2(x[c] * LOG2E) - 1.f;
      F16x8 o;
      o.h[0] = pkrtz(x[0], x[1]); o.h[1] = pkrtz(x[2], x[3]);
      o.h[2] = pkrtz(x[4], x[5]); o.h[3] = pkrtz(x[6], x[7]);
      *(f16x8*)(outp + q8 * 8) = o.v;
    }
  }
}

// ---------------- k_out: x = elu(cat@W1 + b1); out = LN(nodes + x)
// 256 blocks x 256 thr: 16 rows/block, 4 waves k-split (256 k each), LDS combine.
__global__ __launch_bounds__(256) void k_out(const _Float16* __restrict__ hcat,
    const _Float16* __restrict__ W1t, const float* __restrict__ b1,
    const float* __restrict__ nodes, const float* __restrict__ gamma,
    const float* __restrict__ beta, float* __restrict__ out) {
  __shared__ __align__(16) float part[4][16][132];
  int t = threadIdx.x, w = t >> 6, l = t & 63, lr = l & 15, lg = l >> 4;
  int ibase = blockIdx.x * 16;
  f32x4 acc[8] = {};
  const _Float16* arow = hcat + (size_t)(ibase + lr) * 1024 + w * 256;
  const _Float16* bb = W1t + w * 256;
#pragma unroll
  for (int ks = 0; ks < 8; ++ks) {
    int k0 = ks * 32 + lg * 8;
    f16x8 A = *(const f16x8*)(arow + k0);
#pragma unroll
    for (int nt = 0; nt < 8; ++nt) {
      f16x8 B = *(const f16x8*)(bb + (nt * 16 + lr) * 1024 + k0);
      acc[nt] = __builtin_amdgcn_mfma_f32_16x16x32_f16(A, B, acc[nt], 0, 0, 0);
    }
  }
#pragma unroll
  for (int nt = 0; nt < 8; ++nt)
#pragma unroll
    for (int r = 0; r < 4; ++r)
      part[w][lg * 4 + r][nt * 16 + lr] = acc[nt][r];
  __syncthreads();
  int row = t >> 4, c16 = t & 15;
  int d0 = c16 * 8;
  size_t gi = (size_t)(ibase + row) * 128;
  f32x4 pa = {}, pb = {};
#pragma unroll
  for (int q = 0; q < 4; ++q) {
    pa += *(const f32x4*)&part[q][row][d0];
    pb += *(const f32x4*)&part[q][row][d0 + 4];
  }
  f32x4 ba = *(const f32x4*)(b1 + d0), bbv = *(const f32x4*)(b1 + d0 + 4);
  f32x4 na = *(const f32x4*)(nodes + gi + d0), nb = *(const f32x4*)(nodes + gi + d0 + 4);
  float y[8];
  float sum = 0.f, sq = 0.f;
#pragma unroll
  for (int c = 0; c < 4; ++c) {
    float x = pa[c] + ba[c];
    x = x > 0.f ? x : EXP2(x * LOG2E) - 1.f;
    y[c] = x + na[c];
    float x2 = pb[c] + bbv[c];
    x2 = x2 > 0.f ? x2 : EXP2(x2 * LOG2E) - 1.f;
    y[4 + c] = x2 + nb[c];
  }
#pragma unroll
  for (int c = 0; c < 8; ++c) { sum += y[c]; sq += y[c] * y[c]; }
#pragma unroll
  for (int off = 1; off < 16; off <<= 1) {
    sum += __shfl_xor(sum, off, 16);
    sq += __shfl_xor(sq, off, 16);
  }
  float mu = sum * (1.f / 128.f);
  float var = sq * (1.f / 128.f) - mu * mu;
  float rs = __builtin_amdgcn_rsqf(var + EPSLN);
  f32x4 ga = *(const f32x4*)(gamma + d0), gb = *(const f32x4*)(gamma + d0 + 4);
  f32x4 bea = *(const f32x4*)(beta + d0), beb = *(const f32x4*)(beta + d0 + 4);
  f32x4 o0, o1;
#pragma unroll
  for (int c = 0; c < 4; ++c) {
    o0[c] = (y[c] - mu) * rs * ga[c] + bea[c];
    o1[c] = (y[4 + c] - mu) * rs * gb[c] + beb[c];
  }
  *(f32x4*)(out + gi + d0) = o0;
  *(f32x4*)(out + gi + d0 + 4) = o1;
}

extern "C" void kernel_launch(void* const* d_in, const int* in_sizes, int n_in,
                              void* d_out, int out_size, void* d_ws, size_t ws_size,
                              hipStream_t stream) {
  const float* nodes = (const float*)d_in[0];
  const int* adj = (const int*)d_in[1];
  const float* W = (const float*)d_in[2];
  const float* a1 = (const float*)d_in[3];
  const float* a2 = (const float*)d_in[4];
  const float* W1 = (const float*)d_in[5];
  const float* b1 = (const float*)d_in[6];
  const float* gamma = (const float*)d_in[7];
  const float* beta = (const float*)d_in[8];
  float* out = (float*)d_out;
  char* ws = (char*)d_ws;

  const size_t OFF_MASK = 0;                       // 2 MB
  const size_t OFF_WHBT = 2097152;                 // 8.4 MB
  const size_t OFF_F1 = OFF_WHBT + 8388608;        // 128 KB
  const size_t OFF_F2 = OFF_F1 + 131072;           // 128 KB
  const size_t OFF_M2 = OFF_F2 + 131072;           // 256 B
  const size_t OFF_E2T = OFF_M2 + 256;             // 256 KB
  const size_t OFF_WT = OFF_E2T + 262144;          // 256 KB
  const size_t OFF_W1T = OFF_WT + 262144;          // 256 KB
  const size_t OFF_HCAT = OFF_W1T + 262144;        // 8.4 MB

  unsigned long long* maskT = (unsigned long long*)(ws + OFF_MASK);
  _Float16* Whbt = (_Float16*)(ws + OFF_WHBT);
  float* f1L = (float*)(ws + OFF_F1);
  float* f2L = (float*)(ws + OFF_F2);
  float* M2L = (float*)(ws + OFF_M2);
  float2* e2t = (float2*)(ws + OFF_E2T);
  _Float16* Wt = (_Float16*)(ws + OFF_WT);
  _Float16* W1t = (_Float16*)(ws + OFF_W1T);
  _Float16* hcat = (_Float16*)(ws + OFF_HCAT);

  k_packprep<<<17408, 256, 0, stream>>>(adj, maskT, W, W1, Wt, W1t);
  k_wh<<<dim3(64, 8), 256, 0, stream>>>(nodes, Wt, a1, a2, Whbt, f1L, f2L);
  k_m2<<<8, 1024, 0, stream>>>(f2L, M2L, e2t);
  k_attn<<<512, 256, 0, stream>>>(Whbt, f1L, M2L, e2t, maskT, hcat);
  k_out<<<256, 256, 0, stream>>>(hcat, W1t, b1, nodes, gamma, beta, out);
}